// Round 12
// baseline (167.063 us; speedup 1.0000x reference)
//
// decoder_ds — R12: blur phase-1 half-rows + launch_bounds(256,8); sample unchanged.
#include <hip/hip_runtime.h>
#include <hip/hip_fp16.h>
#include <math.h>

#define DD 96
#define VOX (96*96*96)
#define NB 8
#define NC 128
#define L3 125

// ---- blur tiling: 8x16x16 output tile, x->y->z in-place passes ----
#define BTZ 8                  // z output extent
#define BTS 16                 // y/x output extent
#define NBZ 12                 // 96/8
#define NBY 6
#define NBX 6
#define BNTILE (NBZ*NBY*NBX)   // 432 per component
#define BHZ 14                 // z halo extent (8+6)
#define BHY 22                 // y halo extent (16+6)
// LDS: xs[hy*XROW + hz*16 + xo]; XROW=225 (225%32==1 -> y-pass col stride
// walks banks, conflict-free). 22*225 = 4950 floats = 19.8 KB.
#define XROW 225
#define XSN (BHY * XROW)

// ---- sample tiling: (z,y,x) = (12,8,32), x-quads, 4 z-slices/iter ----
#define TZ 12
#define TY 8
#define TX 32
#define NTZ 8                  // 96/12
#define NTY 12                 // 96/8
#define NTX 3
#define STILE (NTZ*NTY*NTX)    // 288 (divisible by 8 -> XCD octants)
#define HZS 14                 // TZ+2
#define HYS 10                 // TY+2
#define HXS 34                 // TX+2
#define HXP 35                 // padded (odd) row stride
#define HLDS (HZS*HYS*HXP)     // 4900 slots = 19600 B
#define NPAIR (HZS*HYS*17)     // 2380 pair-units (17 x-pairs per row)

typedef float vfloat2 __attribute__((ext_vector_type(2)));
typedef float vfloat4 __attribute__((ext_vector_type(4)));
// 8-byte pair load, only 4-byte aligned (proven OK on gfx950 in R4)
typedef float f2u __attribute__((ext_vector_type(2), aligned(4)));

static __device__ __forceinline__ vfloat2 h2f(__half2 h) {
    float2 t = __half22float2(h);
    vfloat2 r; r.x = t.x; r.y = t.y;
    return r;
}

// ---------------- 7^3 box blur (x->y->z, in-place LDS) + alpha tail -------
// Phase 1: TWO threads per (hy,hz) row (8 outputs each, 16-float window from
// 4 aligned float4 loads). Halves the register window vs full-row version;
// __launch_bounds__(256,8) pins VGPR <= 64 so occupancy is LDS-limited
// (8 blocks/CU), not VGPR-limited.
__global__ __launch_bounds__(256, 8) void blur_alpha(
        const float* __restrict__ in, float* __restrict__ out,
        const float* __restrict__ enc,
        const float* __restrict__ c1_w, const float* __restrict__ c1_b,
        const float* __restrict__ f1_w, const float* __restrict__ f1_b,
        float* __restrict__ alpha) {
    __shared__ float xs[XSN];
    __shared__ float red[4];
    int tid = threadIdx.x;

    if (blockIdx.x >= 3 * BNTILE) {
        // -------- alpha path (8 blocks) --------
        int b = blockIdx.x - 3 * BNTILE;
        const float4* e4 = (const float4*)(enc + (size_t)b * NC * L3);
        float s = 0.f;
        for (int j = tid; j < (NC * L3) / 4; j += 256) {
            float4 v = e4[j];
            int f = j * 4;
            s += v.x * c1_w[(f + 0) / L3] * f1_w[(f + 0) % L3];
            s += v.y * c1_w[(f + 1) / L3] * f1_w[(f + 1) % L3];
            s += v.z * c1_w[(f + 2) / L3] * f1_w[(f + 2) % L3];
            s += v.w * c1_w[(f + 3) / L3] * f1_w[(f + 3) % L3];
        }
        for (int off = 32; off > 0; off >>= 1) s += __shfl_down(s, off, 64);
        int lane = tid & 63, wid = tid >> 6;
        if (lane == 0) red[wid] = s;
        __syncthreads();
        if (tid == 0) {
            float tot = red[0] + red[1] + red[2] + red[3];
            float fwsum = 0.f;
            for (int v = 0; v < L3; ++v) fwsum += f1_w[v];
            float x = tot + c1_b[0] * fwsum + f1_b[0];
            alpha[b] = 1.f / (1.f + expf(-x));   // ALPHA_M = 1
        }
        return;
    }

    // -------- blur path (1296 blocks) --------
    int blk = blockIdx.x;
    int c = blk / BNTILE;
    int t = blk % BNTILE;
    int tz = t / (NBY * NBX), ty = (t / NBX) % NBY, tx = t % NBX;
    int bz = tz * BTZ, by = ty * BTS, bx = tx * BTS;
    const float* ib = in + (size_t)c * VOX;

    // phase 1: x-pass, two threads per (hy,hz) row (616 half-row units)
    for (int u = tid; u < 2 * BHY * BHZ; u += 256) {
        int half = (u >= BHY * BHZ) ? 1 : 0;
        int rr = u - half * (BHY * BHZ);
        int hy = rr / BHZ, hz = rr - (rr / BHZ) * BHZ;
        int gz = bz + hz - 3, gy = by + hy - 3;
        float* xrow = &xs[hy * XROW + hz * 16 + half * 8];
        if ((unsigned)gz >= DD || (unsigned)gy >= DD) {
            #pragma unroll
            for (int xo = 0; xo < 8; ++xo) xrow[xo] = 0.f;
            continue;
        }
        const float* rp = ib + (gz * DD + gy) * DD;
        int x0 = bx + half * 8;              // first output x of this half
        int base = x0 - 4;
        if (base < 0) base = 0;              // only when x0 == 0
        if (base > DD - 16) base = DD - 16;  // only when x0 == 88
        const float4* p4 = (const float4*)(rp + base);
        float w[16];
        #pragma unroll
        for (int q = 0; q < 4; ++q) {
            float4 t4 = p4[q];
            w[q * 4 + 0] = t4.x; w[q * 4 + 1] = t4.y;
            w[q * 4 + 2] = t4.z; w[q * 4 + 3] = t4.w;
        }
        // v[j] = in[gx = x0-3+j] for j=0..13, zero outside [0,96)
        float v[14];
        if (x0 == 0) {                       // base=0, gx=j-3
            v[0] = v[1] = v[2] = 0.f;
            #pragma unroll
            for (int j = 3; j < 14; ++j) v[j] = w[j - 3];
        } else if (x0 == DD - 8) {           // base=80, gx=85+j, j>10 -> OOB
            #pragma unroll
            for (int j = 0; j < 11; ++j) v[j] = w[j + 5];
            v[11] = v[12] = v[13] = 0.f;
        } else {                             // base=x0-4, gx-base=j+1
            #pragma unroll
            for (int j = 0; j < 14; ++j) v[j] = w[j + 1];
        }
        float s = v[0] + v[1] + v[2] + v[3] + v[4] + v[5] + v[6];
        xrow[0] = s;
        #pragma unroll
        for (int xo = 1; xo < 8; ++xo) {
            s += v[xo + 6] - v[xo - 1];
            xrow[xo] = s;
        }
    }
    __syncthreads();

    // phase 2: y-pass IN PLACE (running sum per (hz,xo) column, 224 cols)
    if (tid < BHZ * BTS) {
        int hz = tid >> 4, xo = tid & 15;
        int base = hz * 16 + xo;
        float s = 0.f;
        #pragma unroll
        for (int hy = 0; hy < 7; ++hy) s += xs[hy * XROW + base];
        #pragma unroll
        for (int yo = 0; yo < 16; ++yo) {
            float old = xs[yo * XROW + base];
            float nxt = (yo < 15) ? xs[(yo + 7) * XROW + base] : 0.f;
            xs[yo * XROW + base] = s;          // overwrite: ysum[yo]
            s += nxt - old;
        }
    }
    __syncthreads();

    // phase 3: z-pass (running sum) + clip/scale + store (256 threads)
    {
        int yo = tid >> 4, xo = tid & 15;
        int base = yo * XROW + xo;
        float s = 0.f;
        #pragma unroll
        for (int hz = 0; hz < 7; ++hz) s += xs[base + hz * 16];
        float* ob = out + (size_t)c * VOX + (by + yo) * DD + bx + xo;
        #pragma unroll
        for (int zo = 0; zo < BTZ; ++zo) {
            float v = s * (1.0f / 343.0f);
            v = fminf(fmaxf(v, -0.01f), 0.01f) * 96.0f;
            ob[(size_t)(bz + zo) * DD * DD] = v;
            s += xs[base + (zo + 7) * 16] - xs[base + zo * 16];
        }
    }
}

// ---------------- tiled trilinear sampling, (12,8,32) tile, x-quads -------
// LDS-staged gather (direct-gather regressed: VMEM-issue-bound).
// Staging: x-PAIR float2 loads (4B-aligned dwordx2), x-edge fixed by 2
// selects, adjacent LDS writes. Invariant: |disp| <= 0.96 < 1 voxel; halo
// replicates clamped edges, so +1 taps are always adjacent LDS slots.
__global__ __launch_bounds__(256, 8) void sample_tile(
        const float* __restrict__ orig,
        const float* __restrict__ mask,
        const float* __restrict__ field,
        const float* __restrict__ alpha,
        float* __restrict__ out) {
    __shared__ __half2 tile[HLDS];

    int blk = blockIdx.x;
    int b = blk / STILE;
    int r = blk % STILE;
    int o = r & 7;          // octant -> XCD (288 % 8 == 0)
    int l = r >> 3;         // 0..35 within octant
    int zh = o >> 2;        // z half  (4 z-tiles each)
    int yq = o & 3;         // y quarter (3 y-tiles each)
    int lz4 = l / 9, ly3 = (l / 3) % 3, lx3 = l % 3;
    int tz = zh * 4 + lz4;
    int ty = yq * 3 + ly3;
    int tx = lx3;
    int bz = tz * TZ, by = ty * TY, bx = tx * TX;

    const float* ob = orig + (size_t)b * VOX;
    const float* mb = mask + (size_t)b * VOX;
    int tid = threadIdx.x;

    // stage (orig,mask) halo as half2 — pair-units
    for (int u = tid; u < NPAIR; u += 256) {
        int row = u / 17, p = u - row * 17;
        int hz = row / HYS, hy = row - (row / HYS) * HYS;
        int gz = min(max(bz + hz - 1, 0), DD - 1);
        int gy = min(max(by + hy - 1, 0), DD - 1);
        int gx0 = bx - 1 + 2 * p;                 // may be -1 or 95
        int base = min(max(gx0, 0), DD - 2);
        int g = (gz * DD + gy) * DD + base;
        f2u o2 = *(const f2u*)(ob + g);
        f2u m2 = *(const f2u*)(mb + g);
        float oa = (gx0 > DD - 2) ? o2.y : o2.x;  // left tap (clamped)
        float obv = (gx0 < 0) ? o2.x : o2.y;      // right tap (clamped)
        float ma = (gx0 > DD - 2) ? m2.y : m2.x;
        float mbv = (gx0 < 0) ? m2.x : m2.y;
        int idx = (hz * HYS + hy) * HXP + 2 * p;
        tile[idx]     = __floats2half2_rn(oa, ma);
        tile[idx + 1] = __floats2half2_rn(obv, mbv);
    }
    float a = alpha[b];
    __syncthreads();

    const vfloat4* fz4 = (const vfloat4*)field;
    const vfloat4* fy4 = (const vfloat4*)(field + VOX);
    const vfloat4* fx4 = (const vfloat4*)(field + 2 * VOX);
    vfloat4* oD = (vfloat4*)(out);
    vfloat4* oM = (vfloat4*)(out + (size_t)NB * VOX);

    int lz  = tid >> 6;          // 0..3  (z within slice quad)
    int ly  = (tid >> 3) & 7;    // 0..7
    int lxq = tid & 7;           // x-quad 0..7
    int gy  = by + ly;
    int gx0 = bx + 4 * lxq;
    float gyf = (float)gy;
    float gx0f = (float)gx0;
    float c1z = (float)(1 - bz), c1y = (float)(1 - by), c1x = (float)(1 - bx);

    auto samp = [&](float gzf, float dzv, float dyv, float dxv,
                    float gxf) -> vfloat2 {
        float cz = fminf(fmaxf(fmaf(a, dzv, gzf), 0.f), (float)(DD - 1)) + c1z;
        float cy = fminf(fmaxf(fmaf(a, dyv, gyf), 0.f), (float)(DD - 1)) + c1y;
        float cx = fminf(fmaxf(fmaf(a, dxv, gxf), 0.f), (float)(DD - 1)) + c1x;
        float flz = floorf(cz), fly = floorf(cy), flx = floorf(cx);
        float fzf = cz - flz, fyf = cy - fly, fxf = cx - flx;
        int iz = (int)flz, iy = (int)fly, ix = (int)flx;

        const __half2* tp = tile + (iz * HYS + iy) * HXP + ix;
        vfloat2 v000 = h2f(tp[0]);
        vfloat2 v001 = h2f(tp[1]);
        vfloat2 v010 = h2f(tp[HXP]);
        vfloat2 v011 = h2f(tp[HXP + 1]);
        vfloat2 v100 = h2f(tp[HYS * HXP]);
        vfloat2 v101 = h2f(tp[HYS * HXP + 1]);
        vfloat2 v110 = h2f(tp[(HYS + 1) * HXP]);
        vfloat2 v111 = h2f(tp[(HYS + 1) * HXP + 1]);

        vfloat2 FX = {fxf, fxf}, FY = {fyf, fyf}, FZ = {fzf, fzf};
        vfloat2 c00 = v000 + FX * (v001 - v000);
        vfloat2 c01 = v010 + FX * (v011 - v010);
        vfloat2 c10 = v100 + FX * (v101 - v100);
        vfloat2 c11 = v110 + FX * (v111 - v110);
        vfloat2 c0 = c00 + FY * (c01 - c00);
        vfloat2 c1 = c10 + FY * (c11 - c10);
        return c0 + FZ * (c1 - c0);
    };

    int vp4 = (((bz + lz) * DD + gy) * DD + gx0) >> 2;   // float4 index
    vfloat4 dz = fz4[vp4], dy = fy4[vp4], dx = fx4[vp4];
    size_t ob0 = (size_t)b * (VOX / 4);

    #pragma unroll
    for (int it = 0; it < TZ / 4; ++it) {
        vfloat4 dzn = {0,0,0,0}, dyn = {0,0,0,0}, dxn = {0,0,0,0};
        if (it < TZ / 4 - 1) {                 // prefetch next z-quad (static)
            int vq = vp4 + DD * DD;
            dzn = fz4[vq]; dyn = fy4[vq]; dxn = fx4[vq];
        }
        float gzf = (float)(bz + 4 * it + lz);

        vfloat2 r0 = samp(gzf, dz.x, dy.x, dx.x, gx0f);
        vfloat2 r1 = samp(gzf, dz.y, dy.y, dx.y, gx0f + 1.f);
        vfloat2 r2 = samp(gzf, dz.z, dy.z, dx.z, gx0f + 2.f);
        vfloat2 r3 = samp(gzf, dz.w, dy.w, dx.w, gx0f + 3.f);

        vfloat4 vD = {r0.x, r1.x, r2.x, r3.x};
        vfloat4 vM = {r0.y, r1.y, r2.y, r3.y};
        __builtin_nontemporal_store(vD, &oD[ob0 + vp4]);
        __builtin_nontemporal_store(vM, &oM[ob0 + vp4]);

        vp4 += DD * DD;
        dz = dzn; dy = dyn; dx = dxn;
    }
}

extern "C" void kernel_launch(void* const* d_in, const int* in_sizes, int n_in,
                              void* d_out, int out_size, void* d_ws, size_t ws_size,
                              hipStream_t stream) {
    const float* enc   = (const float*)d_in[0];
    const float* orig  = (const float*)d_in[1];
    const float* mask  = (const float*)d_in[2];
    const float* c1_w  = (const float*)d_in[3];
    const float* c1_b  = (const float*)d_in[4];
    const float* f1_w  = (const float*)d_in[5];
    const float* f1_b  = (const float*)d_in[6];
    const float* offs  = (const float*)d_in[7];
    float* out = (float*)d_out;

    float* ws = (float*)d_ws;
    float* alpha = ws;                 // 8 floats
    float* fieldB = ws + 16;           // 3*VOX floats (final blurred field)

    blur_alpha<<<3 * BNTILE + NB, 256, 0, stream>>>(
        offs, fieldB, enc, c1_w, c1_b, f1_w, f1_b, alpha);
    sample_tile<<<NB * STILE, 256, 0, stream>>>(orig, mask, fieldB, alpha, out);
}

// Round 13
// 156.767 us; speedup vs baseline: 1.0657x; 1.0657x over previous
//
// decoder_ds — R13: single-residency-round grids (sample 1536=6/CUx256, blur 1304).
#include <hip/hip_runtime.h>
#include <hip/hip_fp16.h>
#include <math.h>

#define DD 96
#define VOX (96*96*96)
#define NB 8
#define NC 128
#define L3 125

// ---- blur tiling: 8x16x16 output tile, x->y->z in-place passes ----
#define BTZ 8                  // z output extent
#define BTS 16                 // y/x output extent
#define NBZ 12                 // 96/8
#define NBY 6
#define NBX 6
#define BNTILE (NBZ*NBY*NBX)   // 432 per component -> blur grid 1304 (<1536)
#define BHZ 14                 // z halo extent (8+6)
#define BHY 22                 // y halo extent (16+6)
#define XROW 225               // 225%32==1 -> y-pass col reads conflict-free
#define XSN (BHY * XROW)       // 4950 floats = 19.8 KB

// ---- sample tiling: (z,y,x) = (12,12,32), x-pairs, 9 pairs/thread ----
// 192 tiles/batch x 8 = 1536 blocks = EXACTLY 6 blocks/CU x 256 CU:
// one residency round, zero tail (was 2304 blocks = 2 rounds, 2nd 12% full).
#define TZ 12
#define TY 12
#define TX 32
#define NTZ 8                  // 96/12
#define NTY 8                  // 96/12
#define NTX 3
#define STILE (NTZ*NTY*NTX)    // 192 (divisible by 8 -> XCD octants)
#define HZS 14                 // TZ+2
#define HYS 14                 // TY+2
#define HXP 34                 // TX+2, exact (no pad: gather saturates banks)
#define HLDS (HZS*HYS*HXP)     // 6664 half2 = 26656 B -> alloc 27136, 6/CU
#define NPAIR (HZS*HYS*17)     // 3332 staging pair-units

typedef float vfloat2 __attribute__((ext_vector_type(2)));
typedef float vfloat4 __attribute__((ext_vector_type(4)));
// 8-byte pair load, only 4-byte aligned (proven OK on gfx950 in R4)
typedef float f2u __attribute__((ext_vector_type(2), aligned(4)));

static __device__ __forceinline__ vfloat2 h2f(__half2 h) {
    float2 t = __half22float2(h);
    vfloat2 r; r.x = t.x; r.y = t.y;
    return r;
}

// ---------------- 7^3 box blur (x->y->z, in-place LDS) + alpha tail -------
// Phase 1: two threads per (hy,hz) row (8 outputs each, 16-float window).
// launch_bounds(256,6): VGPR cap ~85 (no spill pressure), >=6 blocks/CU ->
// 1304 blocks all resident in one round.
__global__ __launch_bounds__(256, 6) void blur_alpha(
        const float* __restrict__ in, float* __restrict__ out,
        const float* __restrict__ enc,
        const float* __restrict__ c1_w, const float* __restrict__ c1_b,
        const float* __restrict__ f1_w, const float* __restrict__ f1_b,
        float* __restrict__ alpha) {
    __shared__ float xs[XSN];
    __shared__ float red[4];
    int tid = threadIdx.x;

    if (blockIdx.x >= 3 * BNTILE) {
        // -------- alpha path (8 blocks) --------
        int b = blockIdx.x - 3 * BNTILE;
        const float4* e4 = (const float4*)(enc + (size_t)b * NC * L3);
        float s = 0.f;
        for (int j = tid; j < (NC * L3) / 4; j += 256) {
            float4 v = e4[j];
            int f = j * 4;
            s += v.x * c1_w[(f + 0) / L3] * f1_w[(f + 0) % L3];
            s += v.y * c1_w[(f + 1) / L3] * f1_w[(f + 1) % L3];
            s += v.z * c1_w[(f + 2) / L3] * f1_w[(f + 2) % L3];
            s += v.w * c1_w[(f + 3) / L3] * f1_w[(f + 3) % L3];
        }
        for (int off = 32; off > 0; off >>= 1) s += __shfl_down(s, off, 64);
        int lane = tid & 63, wid = tid >> 6;
        if (lane == 0) red[wid] = s;
        __syncthreads();
        if (tid == 0) {
            float tot = red[0] + red[1] + red[2] + red[3];
            float fwsum = 0.f;
            for (int v = 0; v < L3; ++v) fwsum += f1_w[v];
            float x = tot + c1_b[0] * fwsum + f1_b[0];
            alpha[b] = 1.f / (1.f + expf(-x));   // ALPHA_M = 1
        }
        return;
    }

    // -------- blur path (1296 blocks) --------
    int blk = blockIdx.x;
    int c = blk / BNTILE;
    int t = blk % BNTILE;
    int tz = t / (NBY * NBX), ty = (t / NBX) % NBY, tx = t % NBX;
    int bz = tz * BTZ, by = ty * BTS, bx = tx * BTS;
    const float* ib = in + (size_t)c * VOX;

    // phase 1: x-pass, two threads per (hy,hz) row (616 half-row units)
    for (int u = tid; u < 2 * BHY * BHZ; u += 256) {
        int half = (u >= BHY * BHZ) ? 1 : 0;
        int rr = u - half * (BHY * BHZ);
        int hy = rr / BHZ, hz = rr - (rr / BHZ) * BHZ;
        int gz = bz + hz - 3, gy = by + hy - 3;
        float* xrow = &xs[hy * XROW + hz * 16 + half * 8];
        if ((unsigned)gz >= DD || (unsigned)gy >= DD) {
            #pragma unroll
            for (int xo = 0; xo < 8; ++xo) xrow[xo] = 0.f;
            continue;
        }
        const float* rp = ib + (gz * DD + gy) * DD;
        int x0 = bx + half * 8;              // first output x of this half
        int base = x0 - 4;
        if (base < 0) base = 0;              // only when x0 == 0
        if (base > DD - 16) base = DD - 16;  // only when x0 == 88
        const float4* p4 = (const float4*)(rp + base);
        float w[16];
        #pragma unroll
        for (int q = 0; q < 4; ++q) {
            float4 t4 = p4[q];
            w[q * 4 + 0] = t4.x; w[q * 4 + 1] = t4.y;
            w[q * 4 + 2] = t4.z; w[q * 4 + 3] = t4.w;
        }
        // v[j] = in[gx = x0-3+j] for j=0..13, zero outside [0,96)
        float v[14];
        if (x0 == 0) {                       // base=0, gx=j-3
            v[0] = v[1] = v[2] = 0.f;
            #pragma unroll
            for (int j = 3; j < 14; ++j) v[j] = w[j - 3];
        } else if (x0 == DD - 8) {           // base=80, gx=85+j, j>10 -> OOB
            #pragma unroll
            for (int j = 0; j < 11; ++j) v[j] = w[j + 5];
            v[11] = v[12] = v[13] = 0.f;
        } else {                             // base=x0-4, gx-base=j+1
            #pragma unroll
            for (int j = 0; j < 14; ++j) v[j] = w[j + 1];
        }
        float s = v[0] + v[1] + v[2] + v[3] + v[4] + v[5] + v[6];
        xrow[0] = s;
        #pragma unroll
        for (int xo = 1; xo < 8; ++xo) {
            s += v[xo + 6] - v[xo - 1];
            xrow[xo] = s;
        }
    }
    __syncthreads();

    // phase 2: y-pass IN PLACE (running sum per (hz,xo) column, 224 cols)
    if (tid < BHZ * BTS) {
        int hz = tid >> 4, xo = tid & 15;
        int base = hz * 16 + xo;
        float s = 0.f;
        #pragma unroll
        for (int hy = 0; hy < 7; ++hy) s += xs[hy * XROW + base];
        #pragma unroll
        for (int yo = 0; yo < 16; ++yo) {
            float old = xs[yo * XROW + base];
            float nxt = (yo < 15) ? xs[(yo + 7) * XROW + base] : 0.f;
            xs[yo * XROW + base] = s;          // overwrite: ysum[yo]
            s += nxt - old;
        }
    }
    __syncthreads();

    // phase 3: z-pass (running sum) + clip/scale + store (256 threads)
    {
        int yo = tid >> 4, xo = tid & 15;
        int base = yo * XROW + xo;
        float s = 0.f;
        #pragma unroll
        for (int hz = 0; hz < 7; ++hz) s += xs[base + hz * 16];
        float* ob = out + (size_t)c * VOX + (by + yo) * DD + bx + xo;
        #pragma unroll
        for (int zo = 0; zo < BTZ; ++zo) {
            float v = s * (1.0f / 343.0f);
            v = fminf(fmaxf(v, -0.01f), 0.01f) * 96.0f;
            ob[(size_t)(bz + zo) * DD * DD] = v;
            s += xs[base + (zo + 7) * 16] - xs[base + zo * 16];
        }
    }
}

// ---------------- tiled trilinear sampling, (12,12,32) tile, x-pairs ------
// Single residency round: 1536 blocks = 6/CU x 256. LDS-staged gather.
// Invariant: |disp| <= 0.96 < 1 voxel; halo replicates clamped edges, so
// +1 taps are always adjacent LDS slots.
__global__ __launch_bounds__(256, 6) void sample_tile(
        const float* __restrict__ orig,
        const float* __restrict__ mask,
        const float* __restrict__ field,
        const float* __restrict__ alpha,
        float* __restrict__ out) {
    __shared__ __half2 tile[HLDS];

    int blk = blockIdx.x;
    int b = blk / STILE;
    int r = blk % STILE;
    int o = r & 7;          // octant -> XCD (192 % 8 == 0)
    int l = r >> 3;         // 0..23 within octant
    int zh = o >> 2;        // z half (4 z-tiles each)
    int yq = o & 3;         // y quarter (2 y-tiles each)
    int lz4 = l / 6;        // 0..3
    int rem = l - lz4 * 6;
    int ly2 = rem / 3, lx3 = rem - ly2 * 3;
    int tz = zh * 4 + lz4;  // 0..7
    int ty = yq * 2 + ly2;  // 0..7
    int tx = lx3;           // 0..2
    int bz = tz * TZ, by = ty * TY, bx = tx * TX;

    const float* ob = orig + (size_t)b * VOX;
    const float* mb = mask + (size_t)b * VOX;
    int tid = threadIdx.x;

    // stage (orig,mask) halo as half2 — 3332 pair-units
    for (int u = tid; u < NPAIR; u += 256) {
        int row = u / 17, p = u - row * 17;
        int hz = row / HYS, hy = row - (row / HYS) * HYS;
        int gz = min(max(bz + hz - 1, 0), DD - 1);
        int gy = min(max(by + hy - 1, 0), DD - 1);
        int gx0 = bx - 1 + 2 * p;                 // may be -1 or 95
        int base = min(max(gx0, 0), DD - 2);
        int g = (gz * DD + gy) * DD + base;
        f2u o2 = *(const f2u*)(ob + g);
        f2u m2 = *(const f2u*)(mb + g);
        float oa = (gx0 > DD - 2) ? o2.y : o2.x;  // left tap (clamped)
        float obv = (gx0 < 0) ? o2.x : o2.y;      // right tap (clamped)
        float ma = (gx0 > DD - 2) ? m2.y : m2.x;
        float mbv = (gx0 < 0) ? m2.x : m2.y;
        int idx = (hz * HYS + hy) * HXP + 2 * p;
        tile[idx]     = __floats2half2_rn(oa, ma);
        tile[idx + 1] = __floats2half2_rn(obv, mbv);
    }
    float a = alpha[b];
    __syncthreads();

    const float2* fz2 = (const float2*)field;
    const float2* fy2 = (const float2*)(field + VOX);
    const float2* fx2 = (const float2*)(field + 2 * VOX);
    vfloat2* oD = (vfloat2*)(out);
    vfloat2* oM = (vfloat2*)(out + (size_t)NB * VOX);

    int px  = tid & 15;          // x-pair index (fixed per thread)
    int r0  = tid >> 4;          // starting (z,y) row 0..15
    int gx0 = bx + 2 * px;
    float gx0f = (float)gx0;
    float c1z = (float)(1 - bz), c1y = (float)(1 - by), c1x = (float)(1 - bx);

    auto samp = [&](float gzf, float gyf, float gxf, float dzv, float dyv,
                    float dxv) -> vfloat2 {
        float cz = fminf(fmaxf(fmaf(a, dzv, gzf), 0.f), (float)(DD - 1)) + c1z;
        float cy = fminf(fmaxf(fmaf(a, dyv, gyf), 0.f), (float)(DD - 1)) + c1y;
        float cx = fminf(fmaxf(fmaf(a, dxv, gxf), 0.f), (float)(DD - 1)) + c1x;
        float flz = floorf(cz), fly = floorf(cy), flx = floorf(cx);
        float fzf = cz - flz, fyf = cy - fly, fxf = cx - flx;
        int iz = (int)flz, iy = (int)fly, ix = (int)flx;

        const __half2* tp = tile + (iz * HYS + iy) * HXP + ix;
        vfloat2 v000 = h2f(tp[0]);
        vfloat2 v001 = h2f(tp[1]);
        vfloat2 v010 = h2f(tp[HXP]);
        vfloat2 v011 = h2f(tp[HXP + 1]);
        vfloat2 v100 = h2f(tp[HYS * HXP]);
        vfloat2 v101 = h2f(tp[HYS * HXP + 1]);
        vfloat2 v110 = h2f(tp[(HYS + 1) * HXP]);
        vfloat2 v111 = h2f(tp[(HYS + 1) * HXP + 1]);

        vfloat2 FX = {fxf, fxf}, FY = {fyf, fyf}, FZ = {fzf, fzf};
        vfloat2 c00 = v000 + FX * (v001 - v000);
        vfloat2 c01 = v010 + FX * (v011 - v010);
        vfloat2 c10 = v100 + FX * (v101 - v100);
        vfloat2 c11 = v110 + FX * (v111 - v110);
        vfloat2 c0 = c00 + FY * (c01 - c00);
        vfloat2 c1 = c10 + FY * (c11 - c10);
        return c0 + FZ * (c1 - c0);
    };

    size_t ob0 = (size_t)b * (VOX / 2);

    #pragma unroll 3
    for (int k = 0; k < 9; ++k) {            // 9 x-pairs per thread
        int row = r0 + k * 16;               // 0..143
        int z = row / 12;
        int y = row - z * 12;
        int gz = bz + z, gy = by + y;
        int vp2 = ((gz * DD + gy) * DD + gx0) >> 1;

        float2 dz = fz2[vp2], dy = fy2[vp2], dx = fx2[vp2];
        float gzf = (float)gz, gyf = (float)gy;

        vfloat2 s0 = samp(gzf, gyf, gx0f,       dz.x, dy.x, dx.x);
        vfloat2 s1 = samp(gzf, gyf, gx0f + 1.f, dz.y, dy.y, dx.y);

        vfloat2 vD = {s0.x, s1.x};
        vfloat2 vM = {s0.y, s1.y};
        __builtin_nontemporal_store(vD, &oD[ob0 + vp2]);
        __builtin_nontemporal_store(vM, &oM[ob0 + vp2]);
    }
}

extern "C" void kernel_launch(void* const* d_in, const int* in_sizes, int n_in,
                              void* d_out, int out_size, void* d_ws, size_t ws_size,
                              hipStream_t stream) {
    const float* enc   = (const float*)d_in[0];
    const float* orig  = (const float*)d_in[1];
    const float* mask  = (const float*)d_in[2];
    const float* c1_w  = (const float*)d_in[3];
    const float* c1_b  = (const float*)d_in[4];
    const float* f1_w  = (const float*)d_in[5];
    const float* f1_b  = (const float*)d_in[6];
    const float* offs  = (const float*)d_in[7];
    float* out = (float*)d_out;

    float* ws = (float*)d_ws;
    float* alpha = ws;                 // 8 floats
    float* fieldB = ws + 16;           // 3*VOX floats (final blurred field)

    blur_alpha<<<3 * BNTILE + NB, 256, 0, stream>>>(
        offs, fieldB, enc, c1_w, c1_b, f1_w, f1_b, alpha);
    sample_tile<<<NB * STILE, 256, 0, stream>>>(orig, mask, fieldB, alpha, out);
}